// Round 7
// baseline (456.616 us; speedup 1.0000x reference)
//
// ---------------------------------------------------------------------------
// THEORY (Round 7)
// R6 model now closes: per K-step = LDS 576 cyc SERIAL + MFMA 620 cyc because
// the explicit lgkmcnt(0)+sched_barrier(0) pin drains the LDS pipe before the
// first MFMA (m141's mistake). Compiler left alone emits counted
// lgkmcnt(4/3/1/0) and interleaves reads with MFMAs (m97 evidence); the
// classic vmcnt(0)-at-barrier stall is already solved here by raw barriers +
// counted vmcnt(6).
// CHANGE (one variable): remove lgkm/sched/setprio pins from the K-loop.
// Keep: ring-3 LDS, 2 blocks/CU, swizzle, counted vmcnt, grids, epilogues.
// PREDICTED: qkv 128 -> 85-95 us, MfmaUtil 35 -> 48-55%, conflicts 0,
// gemm_out ~26 us, total 412 -> 360-375, flash_attn enters top-5.
// Fallback if MfmaUtil stays ~35: full m201 8-phase port next.
// ---------------------------------------------------------------------------
#include <hip/hip_runtime.h>
#include <hip/hip_bf16.h>

using bf16 = __hip_bfloat16;
typedef __attribute__((ext_vector_type(8))) short short8;
typedef __attribute__((ext_vector_type(4))) float floatx4;
typedef __attribute__((ext_vector_type(2))) float floatx2;

#define GLDS16(g, l)                                                        \
  __builtin_amdgcn_global_load_lds(                                         \
      (const __attribute__((address_space(1))) void*)(g),                   \
      (__attribute__((address_space(3))) void*)(l), 16, 0, 0)

#define MFMA16(a, b, c) __builtin_amdgcn_mfma_f32_16x16x32_bf16(a, b, c, 0, 0, 0)

__device__ __forceinline__ short f2b(float x) {
  union { bf16 h; short s; } u;
  u.h = __float2bfloat16(x);
  return u.s;
}
__device__ __forceinline__ void st(float* p, float v) { *p = v; }
__device__ __forceinline__ void st(bf16* p, float v) { *p = __float2bfloat16(v); }

// ---- DPP cross-lane (stays off the LDS pipe) ------------------------------
template <int CTRL>
__device__ __forceinline__ float dpp_f(float x) {
  return __int_as_float(__builtin_amdgcn_update_dpp(
      0, __float_as_int(x), CTRL, 0xF, 0xF, true));
}
__device__ __forceinline__ float red16_max(float x) {
  x = fmaxf(x, dpp_f<0xB1>(x));    // quad_perm xor1
  x = fmaxf(x, dpp_f<0x4E>(x));    // quad_perm xor2
  x = fmaxf(x, dpp_f<0x141>(x));   // row_half_mirror
  x = fmaxf(x, dpp_f<0x140>(x));   // row_mirror
  return x;
}
__device__ __forceinline__ float red16_sum(float x) {
  x += dpp_f<0xB1>(x);
  x += dpp_f<0x4E>(x);
  x += dpp_f<0x141>(x);
  x += dpp_f<0x140>(x);
  return x;
}

// ---------------------------------------------------------------------------
// fp32 -> bf16 cast, 8 elems/thread, coalesced.
// ---------------------------------------------------------------------------
__global__ void cast_kernel(const float* __restrict__ in, bf16* __restrict__ out,
                            long n) {
  long i = ((long)blockIdx.x * blockDim.x + threadIdx.x) * 8;
  if (i >= n) return;
  floatx4 a = *(const floatx4*)(in + i);
  floatx4 b = *(const floatx4*)(in + i + 4);
  short8 r;
  r[0] = f2b(a[0]); r[1] = f2b(a[1]); r[2] = f2b(a[2]); r[3] = f2b(a[3]);
  r[4] = f2b(b[0]); r[5] = f2b(b[1]); r[6] = f2b(b[2]); r[7] = f2b(b[3]);
  *(short8*)(out + i) = r;
}

// ---------------------------------------------------------------------------
// RoPE cos/sin table: tab[s*64+p] = {cos(s*invf(p)), sin(s*invf(p))}.
// ---------------------------------------------------------------------------
__global__ void rope_tab_kernel(floatx2* __restrict__ tab) {
  const int t = blockIdx.x * blockDim.x + threadIdx.x;   // [0, 131072)
  const int s = t >> 6, p = t & 63;
  const float invf = exp2f(-(float)p * (13.287712379549449f / 64.0f));
  float sn, cs;
  sincosf((float)s * invf, &sn, &cs);
  floatx2 e; e[0] = cs; e[1] = sn;
  tab[t] = e;
}

// ---------------------------------------------------------------------------
// 256x128 / BK=32 core, 256 threads = 4 waves (2Mx2N), wave tile 128x64,
// acc[8][4]. Ring-3 LDS (72 KiB -> 2 blocks/CU). Per K-step:
//   vmcnt(6) -> barrier -> sched_barrier -> [6 GLDS16 (t+2) | 12 ds_read_b128
//   | 32 MFMA, COMPILER-SCHEDULED interleave] -> next step.
// No lgkm pins: compiler emits counted lgkmcnt so MFMAs start as soon as
// their operands land; remaining reads hide under MFMAs.
// Slot-reuse safety: a wave passes barrier t only after lgkm-waiting all its
// step t-1 fragments (they feed its MFMAs), so staging into slot (t-1)%3
// after barrier t cannot race the reads.
// Swizzle: 16B-chunk' = chunk ^ ((row>>1)&3) on global SOURCE + ds_read addr;
// LDS dest linear (rule 21). Measured 0 conflicts (R4-R6).
// ---------------------------------------------------------------------------
__device__ __forceinline__ void gemm_core(
    const bf16* __restrict__ A, const bf16* __restrict__ B, int K,
    long m0, long n0, bf16* As, bf16* Bs, floatx4 (&acc)[8][4])
{
  const int tid  = threadIdx.x;
  const int wave = tid >> 6;
  const int lane = tid & 63;
  const int quad = lane >> 4;
  const int l16  = lane & 15;
  const int wr = wave >> 1;     // 0..1 -> rows wr*128
  const int wc = wave & 1;      // 0..1 -> cols wc*64

  // A staging: 256 rows x 4 chunks = 1024 chunks, 4/thread.
  // B staging: 128 rows x 4 chunks = 512 chunks, 2/thread.
  // c -> row = c>>2, lds chunk = c&3, global chunk = (c&3)^((c>>3)&3).
  long ga[4];
  int aoff[4];
#pragma unroll
  for (int i = 0; i < 4; i++) {
    const int c = i * 256 + tid;
    const int row = c >> 2;
    const int gch = (c & 3) ^ ((c >> 3) & 3);
    ga[i] = (m0 + row) * (long)K + gch * 8;
    aoff[i] = (i * 256 + wave * 64) * 8;     // wave-uniform; +lane*16B in HW
  }
  long gb[2];
  int boff[2];
#pragma unroll
  for (int i = 0; i < 2; i++) {
    const int c = i * 256 + tid;
    const int row = c >> 2;
    const int gch = (c & 3) ^ ((c >> 3) & 3);
    gb[i] = (n0 + row) * (long)K + gch * 8;
    boff[i] = (i * 256 + wave * 64) * 8;
  }

  // read-side swizzled chunk: rows read are 16*x + l16 -> (row>>1)&3 = (l16>>1)&3
  const int qs = (quad ^ ((l16 >> 1) & 3)) * 8;

#pragma unroll
  for (int mi = 0; mi < 8; mi++)
#pragma unroll
    for (int ni = 0; ni < 4; ni++) {
      floatx4 z = {0.f, 0.f, 0.f, 0.f};
      acc[mi][ni] = z;
    }

  const int NT = K >> 5;

  // prologue: stage steps 0,1 into slots 0,1 (6 loads each; 12 in flight)
#pragma unroll
  for (int t = 0; t < 2; t++) {
    bf16* Ad = As + t * 8192;
    bf16* Bd = Bs + t * 4096;
    const long kk = (long)t * 32;
#pragma unroll
    for (int i = 0; i < 4; i++) GLDS16(A + ga[i] + kk, Ad + aoff[i]);
#pragma unroll
    for (int i = 0; i < 2; i++) GLDS16(B + gb[i] + kk, Bd + boff[i]);
  }

  int sl = 0;                    // slot of step t
  for (int t = 0; t < NT; t++) {
    // retire step t's 6 loads (t+1's 6 may stay in flight), then sync.
    if (t < NT - 1) asm volatile("s_waitcnt vmcnt(6)" ::: "memory");
    else            asm volatile("s_waitcnt vmcnt(0)" ::: "memory");
    __builtin_amdgcn_s_barrier();
    __builtin_amdgcn_sched_barrier(0);   // keep body below the barrier

    const bf16* Ab = As + sl * 8192;
    const bf16* Bb = Bs + sl * 4096;

    if (t + 2 < NT) {            // stage step t+2 into slot (t+2)%3
      int s2 = sl + 2; if (s2 >= 3) s2 -= 3;
      bf16* Ad = As + s2 * 8192;
      bf16* Bd = Bs + s2 * 4096;
      const long kk = (long)(t + 2) * 32;
#pragma unroll
      for (int i = 0; i < 4; i++) GLDS16(A + ga[i] + kk, Ad + aoff[i]);
#pragma unroll
      for (int i = 0; i < 2; i++) GLDS16(B + gb[i] + kk, Bd + boff[i]);
    }

    short8 a[8], b[4];
#pragma unroll
    for (int mi = 0; mi < 8; mi++)
      a[mi] = *(const short8*)(Ab + (wr * 128 + mi * 16 + l16) * 32 + qs);
#pragma unroll
    for (int ni = 0; ni < 4; ni++)
      b[ni] = *(const short8*)(Bb + (wc * 64 + ni * 16 + l16) * 32 + qs);

#pragma unroll
    for (int mi = 0; mi < 8; mi++)
#pragma unroll
      for (int ni = 0; ni < 4; ni++)
        acc[mi][ni] = MFMA16(a[mi], b[ni], acc[mi][ni]);

    sl++; if (sl >= 3) sl = 0;
  }
}

// ---------------------------------------------------------------------------
// Fused QKV projection. grid (16, 48): sel = y>>4 picks weight/output,
// n0 = (y&15)*128, m0 = x*256. 768 blocks, 2 co-resident/CU.
// ---------------------------------------------------------------------------
__global__ __launch_bounds__(256, 2) void qkv_gemm(
    const bf16* __restrict__ A,
    const bf16* __restrict__ B0, const bf16* __restrict__ B1,
    const bf16* __restrict__ B2,
    bf16* __restrict__ C0, bf16* __restrict__ C1, bf16* __restrict__ Cvt,
    const floatx2* __restrict__ rtab,
    int M, int N, int K)
{
  __shared__ __align__(16) bf16 As[3 * 8192];
  __shared__ __align__(16) bf16 Bs[3 * 4096];

  const int sel = blockIdx.y >> 4;
  const long m0 = (long)blockIdx.x * 256;
  const long n0 = (long)(blockIdx.y & 15) * 128;
  const bf16* B = (sel == 0) ? B0 : ((sel == 1) ? B1 : B2);

  floatx4 acc[8][4];
  gemm_core(A, B, K, m0, n0, As, Bs, acc);

  const int tid  = threadIdx.x;
  const int wave = tid >> 6;
  const int lane = tid & 63;
  const int quad = lane >> 4;
  const int l16  = lane & 15;
  const int wr = wave >> 1;
  const int wc = wave & 1;

  if (sel < 2) {
    // RoPE epilogue: pairs (2p,2p+1) in adjacent lanes (l16 bit0).
    bf16* C = (sel == 0) ? C0 : C1;
    const float sgn = (l16 & 1) ? 1.0f : -1.0f;
#pragma unroll
    for (int ni = 0; ni < 4; ni++) {
      const int n = (int)n0 + wc * 64 + ni * 16 + l16;   // h*128 + d
      const int p = (n & 127) >> 1;
#pragma unroll
      for (int mi = 0; mi < 8; mi++) {
        floatx4 v = acc[mi][ni];
        const int mbase = (int)m0 + wr * 128 + mi * 16 + quad * 4;
#pragma unroll
        for (int r = 0; r < 4; r++) {
          const int spos = (mbase + r) & 2047;
          const floatx2 cssn = rtab[spos * 64 + p];
          const float pv = dpp_f<0xB1>(v[r]);       // pair partner
          const float outv = v[r] * cssn[0] + pv * (sgn * cssn[1]);
          st(&C[(long)(mbase + r) * N + n], outv);
        }
      }
    }
  } else {
    // transposed V epilogue: v_t[((b*16+h)*128+d)*2048 + s], 4 s packed
#pragma unroll
    for (int ni = 0; ni < 4; ni++) {
      const int n = (int)n0 + wc * 64 + ni * 16 + l16;   // h*128 + d
      const int hh = n >> 7, d = n & 127;
#pragma unroll
      for (int mi = 0; mi < 8; mi++) {
        floatx4 v = acc[mi][ni];
        const int m = (int)m0 + wr * 128 + mi * 16 + quad * 4;
        const int bb = m >> 11, s = m & 2047;
        unsigned long long pk =
            (unsigned long long)(unsigned short)f2b(v[0]) |
            ((unsigned long long)(unsigned short)f2b(v[1]) << 16) |
            ((unsigned long long)(unsigned short)f2b(v[2]) << 32) |
            ((unsigned long long)(unsigned short)f2b(v[3]) << 48);
        *(unsigned long long*)(Cvt + ((long)((bb * 16 + hh) * 128 + d)) * 2048 + s) = pk;
      }
    }
  }
}

// ---------------------------------------------------------------------------
// Final projection GEMM (bf16 x bf16 -> fp32 out), same core.
// grid (16,16) = 256 blocks = exactly 1 full round.
// ---------------------------------------------------------------------------
__global__ __launch_bounds__(256, 2) void gemm_out(
    const bf16* __restrict__ A, const bf16* __restrict__ B,
    float* __restrict__ C, int M, int N, int K)
{
  __shared__ __align__(16) bf16 As[3 * 8192];
  __shared__ __align__(16) bf16 Bs[3 * 4096];
  const long m0 = (long)blockIdx.x * 256;
  const long n0 = (long)blockIdx.y * 128;

  floatx4 acc[8][4];
  gemm_core(A, B, K, m0, n0, As, Bs, acc);

  const int tid  = threadIdx.x;
  const int wave = tid >> 6;
  const int lane = tid & 63;
  const int quad = lane >> 4;
  const int l16  = lane & 15;
  const int wr = wave >> 1;
  const int wc = wave & 1;

#pragma unroll
  for (int mi = 0; mi < 8; mi++)
#pragma unroll
    for (int ni = 0; ni < 4; ni++) {
      floatx4 v = acc[mi][ni];
      const long row = m0 + wr * 128 + mi * 16 + quad * 4;
      const long col = n0 + wc * 64 + ni * 16 + l16;
#pragma unroll
      for (int r = 0; r < 4; r++)
        C[(row + r) * (long)N + col] = v[r];
    }
}

// ---------------------------------------------------------------------------
// Causal flash attention (unchanged this round).
// ---------------------------------------------------------------------------
#define NEG_BIG (-30000.0f)

__global__ __launch_bounds__(256) void flash_attn(
    const bf16* __restrict__ q, const bf16* __restrict__ k,
    const bf16* __restrict__ vt, bf16* __restrict__ o, int S)
{
  __shared__ bf16 Ks[64 * 136];      // K tile row-major, stride 136
  __shared__ bf16 Vt[128 * 72];      // V^T tile: [d][kv], stride 72
  __shared__ bf16 Ps[4][32 * 72];    // per-wave P scratch, stride 72

  const int tid  = threadIdx.x;
  const int wave = tid >> 6;
  const int lane = tid & 63;
  const int quad = lane >> 4;
  const int l16  = lane & 15;

  const int bh = blockIdx.x;
  const int b  = bh >> 4, h = bh & 15;
  const int q0 = ((int)gridDim.y - 1 - (int)blockIdx.y) * 128;  // heavy first

  const bf16* Qb = q + ((long)b * S * 16 + h) * 128;
  const bf16* Kb = k + ((long)b * S * 16 + h) * 128;
  const bf16* Vg = vt + (long)bh * 128 * S;       // [d][s]
  bf16*       Ob = o + ((long)b * S * 16 + h) * 128;

  int kr[4], kc[4], vr[4], vc[4];
#pragma unroll
  for (int it = 0; it < 4; it++) {
    const int c = tid + it * 256;
    kr[it] = c >> 4;  kc[it] = (c & 15) * 8;   // K: 64 rows x 128 d
    vr[it] = c >> 3;  vc[it] = (c & 7) * 8;    // V^T: 128 d x 64 kv
  }

  short8 aq[2][4];
#pragma unroll
  for (int mi = 0; mi < 2; mi++)
#pragma unroll
    for (int kt = 0; kt < 4; kt++)
      aq[mi][kt] = *(const short8*)(
          Qb + (long)(q0 + wave * 32 + mi * 16 + l16) * 2048 + kt * 32 + quad * 8);

  float m_i[2][4], l_i[2][4];
  floatx4 oacc[2][8];
  const floatx4 zero4 = {0.f, 0.f, 0.f, 0.f};
#pragma unroll
  for (int mi = 0; mi < 2; mi++) {
#pragma unroll
    for (int r = 0; r < 4; r++) { m_i[mi][r] = NEG_BIG; l_i[mi][r] = 0.f; }
#pragma unroll
    for (int dt = 0; dt < 8; dt++) oacc[mi][dt] = zero4;
  }

  const float SCL2 = 0.08838834764831845f * 1.4426950408889634f;  // scale*log2e
  const int wrow0 = q0 + wave * 32;
  const int last  = q0 + 64;

  short8 kreg[4], vreg[4];
#pragma unroll
  for (int it = 0; it < 4; it++) {
    kreg[it] = *(const short8*)(Kb + (long)kr[it] * 2048 + kc[it]);
    vreg[it] = *(const short8*)(Vg + (long)vr[it] * S + vc[it]);
  }

  for (int kt0 = 0; kt0 <= last; kt0 += 64) {
    __syncthreads();

#pragma unroll
    for (int it = 0; it < 4; it++) {
      *(short8*)(Ks + kr[it] * 136 + kc[it]) = kreg[it];
      *(short8*)(Vt + vr[it] * 72 + vc[it]) = vreg[it];
    }
    __syncthreads();

    if (kt0 < last) {
      const int n0 = kt0 + 64;
#pragma unroll
      for (int it = 0; it < 4; it++) {
        kreg[it] = *(const short8*)(Kb + (long)(n0 + kr[it]) * 2048 + kc[it]);
        vreg[it] = *(const short8*)(Vg + (long)vr[it] * S + n0 + vc[it]);
      }
    }

    if (kt0 <= wrow0 + 31) {
      floatx4 sc[2][4];
#pragma unroll
      for (int mi = 0; mi < 2; mi++)
#pragma unroll
        for (int nt = 0; nt < 4; nt++) sc[mi][nt] = zero4;
#pragma unroll
      for (int nt = 0; nt < 4; nt++)
#pragma unroll
        for (int kt = 0; kt < 4; kt++) {
          short8 bk = *(const short8*)(Ks + (nt * 16 + l16) * 136 + kt * 32 + quad * 8);
          sc[0][nt] = __builtin_amdgcn_mfma_f32_16x16x32_bf16(aq[0][kt], bk, sc[0][nt], 0, 0, 0);
          sc[1][nt] = __builtin_amdgcn_mfma_f32_16x16x32_bf16(aq[1][kt], bk, sc[1][nt], 0, 0, 0);
        }

      const bool needmask = (kt0 + 63 > wrow0);
      float alpha[2][4];
#pragma unroll
      for (int mi = 0; mi < 2; mi++) {
#pragma unroll
        for (int r = 0; r < 4; r++) {
          const int qr = wrow0 + mi * 16 + quad * 4 + r;
          float mx = NEG_BIG;
          if (needmask) {
#pragma unroll
            for (int nt = 0; nt < 4; nt++) {
              const int kc2 = kt0 + nt * 16 + l16;
              float vsc = sc[mi][nt][r] * SCL2;
              vsc = (kc2 <= qr) ? vsc : NEG_BIG;
              sc[mi][nt][r] = vsc;
              mx = fmaxf(mx, vsc);
            }
          } else {
#pragma unroll
            for (int nt = 0; nt < 4; nt++) {
              float vsc = sc[mi][nt][r] * SCL2;
              sc[mi][nt][r] = vsc;
              mx = fmaxf(mx, vsc);
            }
          }
          mx = red16_max(mx);
          const float mnew = fmaxf(m_i[mi][r], mx);

          alpha[mi][r] = exp2f(m_i[mi][r] - mnew);
          float rs = 0.f;
#pragma unroll
          for (int nt = 0; nt < 4; nt++) {
            float p = exp2f(sc[mi][nt][r] - mnew);
            sc[mi][nt][r] = p;
            rs += p;
          }
          rs = red16_sum(rs);
          l_i[mi][r] = l_i[mi][r] * alpha[mi][r] + rs;
          m_i[mi][r] = mnew;
        }
      }

#pragma unroll
      for (int mi = 0; mi < 2; mi++)
#pragma unroll
        for (int nt = 0; nt < 4; nt++)
#pragma unroll
          for (int r = 0; r < 4; r++)
            Ps[wave][(mi * 16 + quad * 4 + r) * 72 + nt * 16 + l16] =
                __float2bfloat16(sc[mi][nt][r]);

#pragma unroll
      for (int mi = 0; mi < 2; mi++)
#pragma unroll
        for (int dt = 0; dt < 8; dt++)
#pragma unroll
          for (int r = 0; r < 4; r++)
            oacc[mi][dt][r] *= alpha[mi][r];

#pragma unroll
      for (int ks = 0; ks < 2; ks++) {
        short8 ap0 = *(const short8*)(&Ps[wave][(l16) * 72 + ks * 32 + quad * 8]);
        short8 ap1 = *(const short8*)(&Ps[wave][(16 + l16) * 72 + ks * 32 + quad * 8]);
#pragma unroll
        for (int dt = 0; dt < 8; dt++) {
          short8 bv = *(const short8*)(Vt + (dt * 16 + l16) * 72 + ks * 32 + quad * 8);
          oacc[0][dt] = __builtin_amdgcn_mfma_f32_16x16x32_bf16(ap0, bv, oacc[0][dt], 0, 0, 0);
          oacc[1][dt] = __builtin_amdgcn_mfma_f32_16x16x32_bf16(ap1, bv, oacc[1][dt], 0, 0, 0);
        }
      }
    }
  }

#pragma unroll
  for (int mi = 0; mi < 2; mi++)
#pragma unroll
    for (int r = 0; r < 4; r++) {
      const float inv = 1.0f / l_i[mi][r];
      const long s = q0 + wave * 32 + mi * 16 + quad * 4 + r;
#pragma unroll
      for (int dt = 0; dt < 8; dt++)
        Ob[s * 2048 + dt * 16 + l16] = __float2bfloat16(oacc[mi][dt][r] * inv);
    }
}

// ---------------------------------------------------------------------------
extern "C" void kernel_launch(void* const* d_in, const int* in_sizes, int n_in,
                              void* d_out, int out_size, void* d_ws, size_t ws_size,
                              hipStream_t stream) {
  const float* x  = (const float*)d_in[0];
  const float* wq = (const float*)d_in[1];
  const float* wk = (const float*)d_in[2];
  const float* wv = (const float*)d_in[3];
  const float* wo = (const float*)d_in[4];
  float* out = (float*)d_out;

  const int B = 2, S = 2048, D = 2048, H = 16;
  const int M = B * S;                    // 4096
  const long tsz = (long)M * D;           // 8.39M elems
  const long wsz = (long)D * D;           // 4.19M elems

  if (ws_size < 4 * (size_t)tsz * sizeof(bf16)) return;   // 67 MB

  bf16* qb  = (bf16*)d_ws;
  bf16* kb  = qb + tsz;
  bf16* vtb = kb + tsz;                   // transposed V: [b][h][d][s]
  bf16* ab  = vtb + tsz;

  // d_out as scratch: xb (tsz) + wq' (wsz) + wk' (wsz) = exactly out bytes.
  bf16* xb  = (bf16*)d_out;
  bf16* wqb = xb + tsz;
  bf16* wkb = wqb + wsz;
  bf16* wvb = ab;                         // front half of ab (dead until flash)
  floatx2* rtab = (floatx2*)(ab + wsz);   // 1 MB rope table in ab's back half
  bf16* wob = qb;                         // qb dead after flash

  cast_kernel<<<(int)(tsz / 8 / 256), 256, 0, stream>>>(x,  xb,  tsz);
  cast_kernel<<<(int)(wsz / 8 / 256), 256, 0, stream>>>(wq, wqb, wsz);
  cast_kernel<<<(int)(wsz / 8 / 256), 256, 0, stream>>>(wk, wkb, wsz);
  cast_kernel<<<(int)(wsz / 8 / 256), 256, 0, stream>>>(wv, wvb, wsz);
  rope_tab_kernel<<<(S * 64) / 256, 256, 0, stream>>>(rtab);

  qkv_gemm<<<dim3(16, 48), 256, 0, stream>>>(
      xb, wqb, wkb, wvb, qb, kb, vtb, rtab, M, D, D);

  flash_attn<<<dim3(B * H, S / 128), 256, 0, stream>>>(qb, kb, vtb, ab, S);

  cast_kernel<<<(int)(wsz / 8 / 256), 256, 0, stream>>>(wo, wob, wsz);
  gemm_out<<<dim3(16, 16), 256, 0, stream>>>(ab, wob, out, M, D, D);
}

// Round 9
// 417.267 us; speedup vs baseline: 1.0943x; 1.0943x over previous
//
// ---------------------------------------------------------------------------
// THEORY (Round 8, resubmit after infra failure)
// R7 falsified the "remove pins" theory: qkv 128->155, MfmaUtil 35->28.
// The R6 pinned schedule (bulk reads -> lgkm(0) -> setprio -> 32 MFMA) wins
// in the 2-blocks/CU regime -> REVERT GEMM core to R6 exactly.
// Remaining budget: non-qkv ~284 us invariant since R0; flash (<125 us,
// never in top-5) is VALU-bound by arithmetic: ~700 VALU cyc vs 310 MFMA
// vs 430 LDS per wave-tile. Cut VALU:
//  1) q pre-scaled by scale*log2e in qkv epilogue (kills 32 muls/tile),
//  2) defer-max skip (T13, THR=8, wave-uniform __all) skips rescale pass,
//  3) setprio around flash MFMA clusters (T5 attn +4-7%).
// PREDICTED: qkv back to ~125-128 (MfmaUtil ~35, conflicts 0); total
// 412 -> 390-400. If total unchanged -> flash not VALU-bound, pivot to
// m201 8-phase qkv port next round.
// ---------------------------------------------------------------------------
#include <hip/hip_runtime.h>
#include <hip/hip_bf16.h>

using bf16 = __hip_bfloat16;
typedef __attribute__((ext_vector_type(8))) short short8;
typedef __attribute__((ext_vector_type(4))) float floatx4;
typedef __attribute__((ext_vector_type(2))) float floatx2;

#define GLDS16(g, l)                                                        \
  __builtin_amdgcn_global_load_lds(                                         \
      (const __attribute__((address_space(1))) void*)(g),                   \
      (__attribute__((address_space(3))) void*)(l), 16, 0, 0)

#define MFMA16(a, b, c) __builtin_amdgcn_mfma_f32_16x16x32_bf16(a, b, c, 0, 0, 0)

__device__ __forceinline__ short f2b(float x) {
  union { bf16 h; short s; } u;
  u.h = __float2bfloat16(x);
  return u.s;
}
__device__ __forceinline__ void st(float* p, float v) { *p = v; }
__device__ __forceinline__ void st(bf16* p, float v) { *p = __float2bfloat16(v); }

// ---- DPP cross-lane (stays off the LDS pipe) ------------------------------
template <int CTRL>
__device__ __forceinline__ float dpp_f(float x) {
  return __int_as_float(__builtin_amdgcn_update_dpp(
      0, __float_as_int(x), CTRL, 0xF, 0xF, true));
}
__device__ __forceinline__ float red16_max(float x) {
  x = fmaxf(x, dpp_f<0xB1>(x));    // quad_perm xor1
  x = fmaxf(x, dpp_f<0x4E>(x));    // quad_perm xor2
  x = fmaxf(x, dpp_f<0x141>(x));   // row_half_mirror
  x = fmaxf(x, dpp_f<0x140>(x));   // row_mirror
  return x;
}
__device__ __forceinline__ float red16_sum(float x) {
  x += dpp_f<0xB1>(x);
  x += dpp_f<0x4E>(x);
  x += dpp_f<0x141>(x);
  x += dpp_f<0x140>(x);
  return x;
}

// ---------------------------------------------------------------------------
// fp32 -> bf16 cast, 8 elems/thread, coalesced.
// ---------------------------------------------------------------------------
__global__ void cast_kernel(const float* __restrict__ in, bf16* __restrict__ out,
                            long n) {
  long i = ((long)blockIdx.x * blockDim.x + threadIdx.x) * 8;
  if (i >= n) return;
  floatx4 a = *(const floatx4*)(in + i);
  floatx4 b = *(const floatx4*)(in + i + 4);
  short8 r;
  r[0] = f2b(a[0]); r[1] = f2b(a[1]); r[2] = f2b(a[2]); r[3] = f2b(a[3]);
  r[4] = f2b(b[0]); r[5] = f2b(b[1]); r[6] = f2b(b[2]); r[7] = f2b(b[3]);
  *(short8*)(out + i) = r;
}

// ---------------------------------------------------------------------------
// RoPE cos/sin table: tab[s*64+p] = {cos(s*invf(p)), sin(s*invf(p))}.
// ---------------------------------------------------------------------------
__global__ void rope_tab_kernel(floatx2* __restrict__ tab) {
  const int t = blockIdx.x * blockDim.x + threadIdx.x;   // [0, 131072)
  const int s = t >> 6, p = t & 63;
  const float invf = exp2f(-(float)p * (13.287712379549449f / 64.0f));
  float sn, cs;
  sincosf((float)s * invf, &sn, &cs);
  floatx2 e; e[0] = cs; e[1] = sn;
  tab[t] = e;
}

// ---------------------------------------------------------------------------
// 256x128 / BK=32 core (R6, proven): 256 thr = 4 waves (2Mx2N), wave tile
// 128x64, acc[8][4]. Ring-3 LDS (72 KiB -> 2 blocks/CU). Per K-step:
// vmcnt(6) -> barrier -> 12 ds_read | 6 GLDS (t+2) -> lgkm(0) ->
// sched_barrier -> setprio(1) -> 32 MFMA -> setprio(0).
// Swizzle: 16B-chunk' = chunk ^ ((row>>1)&3) on global SOURCE + ds_read addr;
// LDS dest linear (rule 21). Measured 0 conflicts (R4-R7).
// ---------------------------------------------------------------------------
__device__ __forceinline__ void gemm_core(
    const bf16* __restrict__ A, const bf16* __restrict__ B, int K,
    long m0, long n0, bf16* As, bf16* Bs, floatx4 (&acc)[8][4])
{
  const int tid  = threadIdx.x;
  const int wave = tid >> 6;
  const int lane = tid & 63;
  const int quad = lane >> 4;
  const int l16  = lane & 15;
  const int wr = wave >> 1;     // 0..1 -> rows wr*128
  const int wc = wave & 1;      // 0..1 -> cols wc*64

  long ga[4];
  int aoff[4];
#pragma unroll
  for (int i = 0; i < 4; i++) {
    const int c = i * 256 + tid;
    const int row = c >> 2;
    const int gch = (c & 3) ^ ((c >> 3) & 3);
    ga[i] = (m0 + row) * (long)K + gch * 8;
    aoff[i] = (i * 256 + wave * 64) * 8;     // wave-uniform; +lane*16B in HW
  }
  long gb[2];
  int boff[2];
#pragma unroll
  for (int i = 0; i < 2; i++) {
    const int c = i * 256 + tid;
    const int row = c >> 2;
    const int gch = (c & 3) ^ ((c >> 3) & 3);
    gb[i] = (n0 + row) * (long)K + gch * 8;
    boff[i] = (i * 256 + wave * 64) * 8;
  }

  // read-side swizzled chunk: rows read are 16*x + l16 -> (row>>1)&3 = (l16>>1)&3
  const int qs = (quad ^ ((l16 >> 1) & 3)) * 8;

#pragma unroll
  for (int mi = 0; mi < 8; mi++)
#pragma unroll
    for (int ni = 0; ni < 4; ni++) {
      floatx4 z = {0.f, 0.f, 0.f, 0.f};
      acc[mi][ni] = z;
    }

  const int NT = K >> 5;

  // prologue: stage steps 0,1 into slots 0,1 (6 loads each; 12 in flight)
#pragma unroll
  for (int t = 0; t < 2; t++) {
    bf16* Ad = As + t * 8192;
    bf16* Bd = Bs + t * 4096;
    const long kk = (long)t * 32;
#pragma unroll
    for (int i = 0; i < 4; i++) GLDS16(A + ga[i] + kk, Ad + aoff[i]);
#pragma unroll
    for (int i = 0; i < 2; i++) GLDS16(B + gb[i] + kk, Bd + boff[i]);
  }

  int sl = 0;                    // slot of step t
  for (int t = 0; t < NT; t++) {
    // retire step t's 6 loads (t+1's 6 may stay in flight), then sync.
    if (t < NT - 1) asm volatile("s_waitcnt vmcnt(6)" ::: "memory");
    else            asm volatile("s_waitcnt vmcnt(0)" ::: "memory");
    __builtin_amdgcn_s_barrier();

    const bf16* Ab = As + sl * 8192;
    const bf16* Bb = Bs + sl * 4096;

    short8 a[8], b[4];
#pragma unroll
    for (int mi = 0; mi < 8; mi++)
      a[mi] = *(const short8*)(Ab + (wr * 128 + mi * 16 + l16) * 32 + qs);
#pragma unroll
    for (int ni = 0; ni < 4; ni++)
      b[ni] = *(const short8*)(Bb + (wc * 64 + ni * 16 + l16) * 32 + qs);

    if (t + 2 < NT) {            // stage step t+2 into slot (t+2)%3
      int s2 = sl + 2; if (s2 >= 3) s2 -= 3;
      bf16* Ad = As + s2 * 8192;
      bf16* Bd = Bs + s2 * 4096;
      const long kk = (long)(t + 2) * 32;
#pragma unroll
      for (int i = 0; i < 4; i++) GLDS16(A + ga[i] + kk, Ad + aoff[i]);
#pragma unroll
      for (int i = 0; i < 2; i++) GLDS16(B + gb[i] + kk, Bd + boff[i]);
    }

    asm volatile("s_waitcnt lgkmcnt(0)" ::: "memory");
    __builtin_amdgcn_sched_barrier(0);
    __builtin_amdgcn_s_setprio(1);
#pragma unroll
    for (int mi = 0; mi < 8; mi++)
#pragma unroll
      for (int ni = 0; ni < 4; ni++)
        acc[mi][ni] = MFMA16(a[mi], b[ni], acc[mi][ni]);
    __builtin_amdgcn_s_setprio(0);

    sl++; if (sl >= 3) sl = 0;
  }
}

// ---------------------------------------------------------------------------
// Fused QKV projection. grid (16, 48): sel = y>>4 picks weight/output,
// n0 = (y&15)*128, m0 = x*256. 768 blocks, 2 co-resident/CU.
// q output is PRE-SCALED by scale*log2e (flash consumes scores directly).
// ---------------------------------------------------------------------------
__global__ __launch_bounds__(256, 2) void qkv_gemm(
    const bf16* __restrict__ A,
    const bf16* __restrict__ B0, const bf16* __restrict__ B1,
    const bf16* __restrict__ B2,
    bf16* __restrict__ C0, bf16* __restrict__ C1, bf16* __restrict__ Cvt,
    const floatx2* __restrict__ rtab,
    int M, int N, int K)
{
  __shared__ __align__(16) bf16 As[3 * 8192];
  __shared__ __align__(16) bf16 Bs[3 * 4096];

  const int sel = blockIdx.y >> 4;
  const long m0 = (long)blockIdx.x * 256;
  const long n0 = (long)(blockIdx.y & 15) * 128;
  const bf16* B = (sel == 0) ? B0 : ((sel == 1) ? B1 : B2);

  floatx4 acc[8][4];
  gemm_core(A, B, K, m0, n0, As, Bs, acc);

  const int tid  = threadIdx.x;
  const int wave = tid >> 6;
  const int lane = tid & 63;
  const int quad = lane >> 4;
  const int l16  = lane & 15;
  const int wr = wave >> 1;
  const int wc = wave & 1;

  if (sel < 2) {
    // RoPE epilogue: pairs (2p,2p+1) in adjacent lanes (l16 bit0).
    bf16* C = (sel == 0) ? C0 : C1;
    const float qscale = (sel == 0)
        ? (0.08838834764831845f * 1.4426950408889634f) : 1.0f;
    const float sgn = (l16 & 1) ? 1.0f : -1.0f;
#pragma unroll
    for (int ni = 0; ni < 4; ni++) {
      const int n = (int)n0 + wc * 64 + ni * 16 + l16;   // h*128 + d
      const int p = (n & 127) >> 1;
#pragma unroll
      for (int mi = 0; mi < 8; mi++) {
        floatx4 v = acc[mi][ni];
        const int mbase = (int)m0 + wr * 128 + mi * 16 + quad * 4;
#pragma unroll
        for (int r = 0; r < 4; r++) {
          const int spos = (mbase + r) & 2047;
          const floatx2 cssn = rtab[spos * 64 + p];
          const float pv = dpp_f<0xB1>(v[r]);       // pair partner
          const float outv = (v[r] * cssn[0] + pv * (sgn * cssn[1])) * qscale;
          st(&C[(long)(mbase + r) * N + n], outv);
        }
      }
    }
  } else {
    // transposed V epilogue: v_t[((b*16+h)*128+d)*2048 + s], 4 s packed
#pragma unroll
    for (int ni = 0; ni < 4; ni++) {
      const int n = (int)n0 + wc * 64 + ni * 16 + l16;   // h*128 + d
      const int hh = n >> 7, d = n & 127;
#pragma unroll
      for (int mi = 0; mi < 8; mi++) {
        floatx4 v = acc[mi][ni];
        const int m = (int)m0 + wr * 128 + mi * 16 + quad * 4;
        const int bb = m >> 11, s = m & 2047;
        unsigned long long pk =
            (unsigned long long)(unsigned short)f2b(v[0]) |
            ((unsigned long long)(unsigned short)f2b(v[1]) << 16) |
            ((unsigned long long)(unsigned short)f2b(v[2]) << 32) |
            ((unsigned long long)(unsigned short)f2b(v[3]) << 48);
        *(unsigned long long*)(Cvt + ((long)((bb * 16 + hh) * 128 + d)) * 2048 + s) = pk;
      }
    }
  }
}

// ---------------------------------------------------------------------------
// Final projection GEMM (bf16 x bf16 -> fp32 out), same core.
// grid (16,16) = 256 blocks = exactly 1 full round.
// ---------------------------------------------------------------------------
__global__ __launch_bounds__(256, 2) void gemm_out(
    const bf16* __restrict__ A, const bf16* __restrict__ B,
    float* __restrict__ C, int M, int N, int K)
{
  __shared__ __align__(16) bf16 As[3 * 8192];
  __shared__ __align__(16) bf16 Bs[3 * 4096];
  const long m0 = (long)blockIdx.x * 256;
  const long n0 = (long)blockIdx.y * 128;

  floatx4 acc[8][4];
  gemm_core(A, B, K, m0, n0, As, Bs, acc);

  const int tid  = threadIdx.x;
  const int wave = tid >> 6;
  const int lane = tid & 63;
  const int quad = lane >> 4;
  const int l16  = lane & 15;
  const int wr = wave >> 1;
  const int wc = wave & 1;

#pragma unroll
  for (int mi = 0; mi < 8; mi++)
#pragma unroll
    for (int ni = 0; ni < 4; ni++) {
      floatx4 v = acc[mi][ni];
      const long row = m0 + wr * 128 + mi * 16 + quad * 4;
      const long col = n0 + wc * 64 + ni * 16 + l16;
#pragma unroll
      for (int r = 0; r < 4; r++)
        C[(row + r) * (long)N + col] = v[r];
    }
}

// ---------------------------------------------------------------------------
// Causal flash attention. q arrives pre-scaled by scale*log2e.
// VALU cuts this round: defer-max (T13, THR=8) two-pass softmax with
// wave-uniform skip of the rescale pass; setprio around MFMA clusters (T5).
// ---------------------------------------------------------------------------
#define NEG_BIG (-30000.0f)

__global__ __launch_bounds__(256) void flash_attn(
    const bf16* __restrict__ q, const bf16* __restrict__ k,
    const bf16* __restrict__ vt, bf16* __restrict__ o, int S)
{
  __shared__ bf16 Ks[64 * 136];      // K tile row-major, stride 136
  __shared__ bf16 Vt[128 * 72];      // V^T tile: [d][kv], stride 72
  __shared__ bf16 Ps[4][32 * 72];    // per-wave P scratch, stride 72

  const int tid  = threadIdx.x;
  const int wave = tid >> 6;
  const int lane = tid & 63;
  const int quad = lane >> 4;
  const int l16  = lane & 15;

  const int bh = blockIdx.x;
  const int b  = bh >> 4, h = bh & 15;
  const int q0 = ((int)gridDim.y - 1 - (int)blockIdx.y) * 128;  // heavy first

  const bf16* Qb = q + ((long)b * S * 16 + h) * 128;
  const bf16* Kb = k + ((long)b * S * 16 + h) * 128;
  const bf16* Vg = vt + (long)bh * 128 * S;       // [d][s]
  bf16*       Ob = o + ((long)b * S * 16 + h) * 128;

  int kr[4], kc[4], vr[4], vc[4];
#pragma unroll
  for (int it = 0; it < 4; it++) {
    const int c = tid + it * 256;
    kr[it] = c >> 4;  kc[it] = (c & 15) * 8;   // K: 64 rows x 128 d
    vr[it] = c >> 3;  vc[it] = (c & 7) * 8;    // V^T: 128 d x 64 kv
  }

  short8 aq[2][4];
#pragma unroll
  for (int mi = 0; mi < 2; mi++)
#pragma unroll
    for (int kt = 0; kt < 4; kt++)
      aq[mi][kt] = *(const short8*)(
          Qb + (long)(q0 + wave * 32 + mi * 16 + l16) * 2048 + kt * 32 + quad * 8);

  float m_i[2][4], l_i[2][4];
  floatx4 oacc[2][8];
  const floatx4 zero4 = {0.f, 0.f, 0.f, 0.f};
#pragma unroll
  for (int mi = 0; mi < 2; mi++) {
#pragma unroll
    for (int r = 0; r < 4; r++) { m_i[mi][r] = NEG_BIG; l_i[mi][r] = 0.f; }
#pragma unroll
    for (int dt = 0; dt < 8; dt++) oacc[mi][dt] = zero4;
  }

  const int wrow0 = q0 + wave * 32;
  const int last  = q0 + 64;

  short8 kreg[4], vreg[4];
#pragma unroll
  for (int it = 0; it < 4; it++) {
    kreg[it] = *(const short8*)(Kb + (long)kr[it] * 2048 + kc[it]);
    vreg[it] = *(const short8*)(Vg + (long)vr[it] * S + vc[it]);
  }

  for (int kt0 = 0; kt0 <= last; kt0 += 64) {
    __syncthreads();

#pragma unroll
    for (int it = 0; it < 4; it++) {
      *(short8*)(Ks + kr[it] * 136 + kc[it]) = kreg[it];
      *(short8*)(Vt + vr[it] * 72 + vc[it]) = vreg[it];
    }
    __syncthreads();

    if (kt0 < last) {
      const int n0 = kt0 + 64;
#pragma unroll
      for (int it = 0; it < 4; it++) {
        kreg[it] = *(const short8*)(Kb + (long)(n0 + kr[it]) * 2048 + kc[it]);
        vreg[it] = *(const short8*)(Vg + (long)vr[it] * S + n0 + vc[it]);
      }
    }

    if (kt0 <= wrow0 + 31) {
      floatx4 sc[2][4];
#pragma unroll
      for (int mi = 0; mi < 2; mi++)
#pragma unroll
        for (int nt = 0; nt < 4; nt++) sc[mi][nt] = zero4;

      __builtin_amdgcn_s_setprio(1);
#pragma unroll
      for (int nt = 0; nt < 4; nt++)
#pragma unroll
        for (int kt = 0; kt < 4; kt++) {
          short8 bk = *(const short8*)(Ks + (nt * 16 + l16) * 136 + kt * 32 + quad * 8);
          sc[0][nt] = __builtin_amdgcn_mfma_f32_16x16x32_bf16(aq[0][kt], bk, sc[0][nt], 0, 0, 0);
          sc[1][nt] = __builtin_amdgcn_mfma_f32_16x16x32_bf16(aq[1][kt], bk, sc[1][nt], 0, 0, 0);
        }
      __builtin_amdgcn_s_setprio(0);

      // ---- pass 1: mask + row max (scores already scaled, log2 domain) ----
      const bool needmask = (kt0 + 63 > wrow0);
      float mx[2][4];
      int allskip = 1;
#pragma unroll
      for (int mi = 0; mi < 2; mi++) {
#pragma unroll
        for (int r = 0; r < 4; r++) {
          const int qr = wrow0 + mi * 16 + quad * 4 + r;
          float m = NEG_BIG;
          if (needmask) {
#pragma unroll
            for (int nt = 0; nt < 4; nt++) {
              const int kc2 = kt0 + nt * 16 + l16;
              float vsc = (kc2 <= qr) ? sc[mi][nt][r] : NEG_BIG;
              sc[mi][nt][r] = vsc;
              m = fmaxf(m, vsc);
            }
          } else {
#pragma unroll
            for (int nt = 0; nt < 4; nt++) m = fmaxf(m, sc[mi][nt][r]);
          }
          m = red16_max(m);
          mx[mi][r] = m;
          allskip &= (m <= m_i[mi][r] + 8.0f) ? 1 : 0;
        }
      }

      // ---- defer-max: rescale only when some row max grew past THR=8 ----
      if (!__all(allskip)) {
#pragma unroll
        for (int mi = 0; mi < 2; mi++) {
#pragma unroll
          for (int r = 0; r < 4; r++) {
            const float mnew = fmaxf(m_i[mi][r], mx[mi][r]);
            const float alpha = exp2f(m_i[mi][r] - mnew);
            m_i[mi][r] = mnew;
            l_i[mi][r] *= alpha;
#pragma unroll
            for (int dt = 0; dt < 8; dt++) oacc[mi][dt][r] *= alpha;
          }
        }
      }

      // ---- pass 2: exp + row sum against (possibly stale) m_i ----
#pragma unroll
      for (int mi = 0; mi < 2; mi++) {
#pragma unroll
        for (int r = 0; r < 4; r++) {
          float rs = 0.f;
#pragma unroll
          for (int nt = 0; nt < 4; nt++) {
            float p = exp2f(sc[mi][nt][r] - m_i[mi][r]);
            sc[mi][nt][r] = p;
            rs += p;
          }
          rs = red16_sum(rs);
          l_i[mi][r] += rs;
        }
      }

#pragma unroll
      for (int mi = 0; mi < 2; mi++)
#pragma unroll
        for (int nt = 0; nt < 4; nt++)
#pragma unroll
          for (int r = 0; r < 4; r++)
            Ps[wave][(mi * 16 + quad * 4 + r) * 72 + nt * 16 + l16] =
                __float2bfloat16(sc[mi][nt][r]);

      __builtin_amdgcn_s_setprio(1);
#pragma unroll
      for (int ks = 0; ks < 2; ks++) {
        short8 ap0 = *(const short8*)(&Ps[wave][(l16) * 72 + ks * 32 + quad * 8]);
        short8 ap1 = *(const short8*)(&Ps[wave][(16 + l16) * 72 + ks * 32 + quad * 8]);
#pragma unroll
        for (int dt = 0; dt < 8; dt++) {
          short8 bv = *(const short8*)(Vt + (dt * 16 + l16) * 72 + ks * 32 + quad * 8);
          oacc[0][dt] = __builtin_amdgcn_mfma_f32_16x16x32_bf16(ap0, bv, oacc[0][dt], 0, 0, 0);
          oacc[1][dt] = __builtin_amdgcn_mfma_f32_16x16x32_bf16(ap1, bv, oacc[1][dt], 0, 0, 0);
        }
      }
      __builtin_amdgcn_s_setprio(0);
    }
  }

#pragma unroll
  for (int mi = 0; mi < 2; mi++)
#pragma unroll
    for (int r = 0; r < 4; r++) {
      const float inv = 1.0f / l_i[mi][r];
      const long s = q0 + wave * 32 + mi * 16 + quad * 4 + r;
#pragma unroll
      for (int dt = 0; dt < 8; dt++)
        Ob[s * 2048 + dt * 16 + l16] = __float2bfloat16(oacc[mi][dt][r] * inv);
    }
}

// ---------------------------------------------------------------------------
extern "C" void kernel_launch(void* const* d_in, const int* in_sizes, int n_in,
                              void* d_out, int out_size, void* d_ws, size_t ws_size,
                              hipStream_t stream) {
  const float* x  = (const float*)d_in[0];
  const float* wq = (const float*)d_in[1];
  const float* wk = (const float*)d_in[2];
  const float* wv = (const float*)d_in[3];
  const float* wo = (const float*)d_in[4];
  float* out = (float*)d_out;

  const int B = 2, S = 2048, D = 2048, H = 16;
  const int M = B * S;                    // 4096
  const long tsz = (long)M * D;           // 8.39M elems
  const long wsz = (long)D * D;           // 4.19M elems

  if (ws_size < 4 * (size_t)tsz * sizeof(bf16)) return;   // 67 MB

  bf16* qb  = (bf16*)d_ws;
  bf16* kb  = qb + tsz;
  bf16* vtb = kb + tsz;                   // transposed V: [b][h][d][s]
  bf16* ab  = vtb + tsz;

  // d_out as scratch: xb (tsz) + wq' (wsz) + wk' (wsz) = exactly out bytes.
  bf16* xb  = (bf16*)d_out;
  bf16* wqb = xb + tsz;
  bf16* wkb = wqb + wsz;
  bf16* wvb = ab;                         // front half of ab (dead until flash)
  floatx2* rtab = (floatx2*)(ab + wsz);   // 1 MB rope table in ab's back half
  bf16* wob = qb;                         // qb dead after flash

  cast_kernel<<<(int)(tsz / 8 / 256), 256, 0, stream>>>(x,  xb,  tsz);
  cast_kernel<<<(int)(wsz / 8 / 256), 256, 0, stream>>>(wq, wqb, wsz);
  cast_kernel<<<(int)(wsz / 8 / 256), 256, 0, stream>>>(wk, wkb, wsz);
  cast_kernel<<<(int)(wsz / 8 / 256), 256, 0, stream>>>(wv, wvb, wsz);
  rope_tab_kernel<<<(S * 64) / 256, 256, 0, stream>>>(rtab);

  qkv_gemm<<<dim3(16, 48), 256, 0, stream>>>(
      xb, wqb, wkb, wvb, qb, kb, vtb, rtab, M, D, D);

  flash_attn<<<dim3(B * H, S / 128), 256, 0, stream>>>(qb, kb, vtb, ab, S);

  cast_kernel<<<(int)(wsz / 8 / 256), 256, 0, stream>>>(wo, wob, wsz);
  gemm_out<<<dim3(16, 16), 256, 0, stream>>>(ab, wob, out, M, D, D);
}